// Round 11
// baseline (320.530 us; speedup 1.0000x reference)
//
#include <hip/hip_runtime.h>
#include <hip/hip_fp16.h>
#include <math.h>

// ---------------------------------------------------------------------------
// SplineCNN (K=4, dim=2, deg=2). v11: k_ag2 gather via even/odd-channel uint
// loads (half the VMEM requests), conflict-free agg LDS writes (p=k*32+ch,
// b32 interleaved), b64 LDS reads at odd-8B strides (~4-way vs 8-way).
// ---------------------------------------------------------------------------

typedef _Float16 half8 __attribute__((ext_vector_type(8)));
typedef _Float16 half4 __attribute__((ext_vector_type(4)));
typedef float    f32x4 __attribute__((ext_vector_type(4)));
typedef unsigned uintx2 __attribute__((ext_vector_type(2)));
typedef unsigned uintx4 __attribute__((ext_vector_type(4)));

#define ACHUNK 4096   // edges per partition WG (16 per thread)

__device__ __forceinline__ void bspline4(float a, float B[4]) {
    a = fminf(fmaxf(a, 0.f), 1.f);
    float v  = a * 2.0f;          // K - DEG = 2
    float kv = floorf(v);
    float t  = v - kv;
    int   ik = (int)kv;           // 0..2
    float b0 = 0.5f * (1.f - t) * (1.f - t);
    float b1 = (t - t * t) + 0.5f;
    float b2 = 0.5f * t * t;
    int c0 = ik;
    int c1 = ik + 1;
    int c2 = ik + 2; if (c2 > 3) c2 = 3;
#pragma unroll
    for (int j = 0; j < 4; ++j)
        B[j] = (c0 == j ? b0 : 0.f) + (c1 == j ? b1 : 0.f) + (c2 == j ? b2 : 0.f);
}

__device__ __forceinline__ float eluf(float x) {
    return x > 0.f ? x : expm1f(x);
}

__device__ __forceinline__ void unpack_basis(uint4 rec, float bu[4], float bv[4]) {
    float2 f01 = __half22float2(*(const __half2*)&rec.y);
    float2 f23 = __half22float2(*(const __half2*)&rec.z);
    float2 f45 = __half22float2(*(const __half2*)&rec.w);
    bu[0] = f01.x; bu[1] = f01.y; bu[2] = f23.x;
    bu[3] = 1.f - (bu[0] + bu[1] + bu[2]);
    bv[0] = f23.y; bv[1] = f45.x; bv[2] = f45.y;
    bv[3] = 1.f - (bv[0] + bv[1] + bv[2]);
}

__device__ __forceinline__ uint4 make_edge_rec(unsigned src, float u, float v) {
    float Bu[4], Bv[4];
    bspline4(u, Bu);
    bspline4(v, Bv);
    __half2 p01 = __floats2half2_rn(Bu[0], Bu[1]);
    __half2 p23 = __floats2half2_rn(Bu[2], Bv[0]);
    __half2 p45 = __floats2half2_rn(Bv[1], Bv[2]);
    uint4 rec;
    rec.x = src;
    rec.y = *(const unsigned*)&p01;
    rec.z = *(const unsigned*)&p23;
    rec.w = *(const unsigned*)&p45;
    return rec;
}

// ---------------- Phase A: bucketed partition (bucket = dst >> 8) ----------------

__global__ void kA1_hist(const int* __restrict__ dst, int E, int* __restrict__ cnt,
                         int nWG, int NBUK) {
    extern __shared__ int hist[];   // NBUK ints
    int wg = blockIdx.x, tid = threadIdx.x;
    for (int b = tid; b < NBUK; b += 256) hist[b] = 0;
    __syncthreads();
    int base = wg * ACHUNK;
    int end  = base + ACHUNK; if (end > E) end = E;
    for (int i = base + tid; i < end; i += 256)
        atomicAdd(&hist[dst[i] >> 8], 1);
    __syncthreads();
    for (int b = tid; b < NBUK; b += 256) cnt[b * nWG + wg] = hist[b];
}

__global__ void k_scan1(const int* __restrict__ in, int M,
                        int* __restrict__ outp, int* __restrict__ blockSums) {
    __shared__ int wsum[4];
    int tid  = threadIdx.x;
    int base = blockIdx.x * 1024 + tid * 4;
    int d0 = (base + 0) < M ? in[base + 0] : 0;
    int d1 = (base + 1) < M ? in[base + 1] : 0;
    int d2 = (base + 2) < M ? in[base + 2] : 0;
    int d3 = (base + 3) < M ? in[base + 3] : 0;
    int s4 = d0 + d1 + d2 + d3;
    int lane = tid & 63, wid = tid >> 6;
    int inc = s4;
#pragma unroll
    for (int off = 1; off < 64; off <<= 1) {
        int t = __shfl_up(inc, off);
        if (lane >= off) inc += t;
    }
    if (lane == 63) wsum[wid] = inc;
    __syncthreads();
    if (tid == 0) {
        int acc = 0;
#pragma unroll
        for (int w = 0; w < 4; ++w) { int t = wsum[w]; wsum[w] = acc; acc += t; }
    }
    __syncthreads();
    int ebase = wsum[wid] + inc - s4;
    if ((base + 0) < M) outp[base + 0] = ebase;
    if ((base + 1) < M) outp[base + 1] = ebase + d0;
    if ((base + 2) < M) outp[base + 2] = ebase + d0 + d1;
    if ((base + 3) < M) outp[base + 3] = ebase + d0 + d1 + d2;
    if (tid == 255) blockSums[blockIdx.x] = ebase + s4;
}

// capacity 512 (2 elems per thread)
__global__ void k_scan2(const int* __restrict__ blockSums, int NB, int* __restrict__ blockOff) {
    __shared__ int sh[256];
    int tid = threadIdx.x;
    int i0 = 2 * tid, i1 = 2 * tid + 1;
    int a = (i0 < NB) ? blockSums[i0] : 0;
    int b = (i1 < NB) ? blockSums[i1] : 0;
    int p = a + b;
    sh[tid] = p;
    __syncthreads();
    for (int off = 1; off < 256; off <<= 1) {
        int v = (tid >= off) ? sh[tid - off] : 0;
        __syncthreads();
        sh[tid] += v;
        __syncthreads();
    }
    int excl = sh[tid] - p;
    if (i0 < NB) blockOff[i0] = excl;
    if (i1 < NB) blockOff[i1] = excl + a;
}

__global__ void k_scan3b(int* __restrict__ arr, const int* __restrict__ blockOff, int M) {
    int i = blockIdx.x * blockDim.x + threadIdx.x;
    if (i < M) arr[i] += blockOff[i >> 10];
}

// fill pass: whole chunk staged in LDS; reads coalesced-once, writes runs.
__global__ __launch_bounds__(256) void kA2_fill(
    const int* __restrict__ ei, const float* __restrict__ attr, int E,
    const int* __restrict__ offs, int nWG, int NBUK,
    uint4* __restrict__ buf1, unsigned char* __restrict__ dl1) {
    extern __shared__ int lds[];
    int*      hist  = lds;                         // NBUK (becomes pref)
    int*      srcS  = hist + NBUK;                 // ACHUNK
    unsigned* attrS = (unsigned*)(srcS + ACHUNK);  // ACHUNK (fp16 u,v)
    unsigned* meta  = attrS + ACHUNK;              // ACHUNK
    __shared__ int wsum[4];
    int wg = blockIdx.x, tid = threadIdx.x;
    int base  = wg * ACHUNK;
    int csize = E - base; if (csize > ACHUNK) csize = ACHUNK;

    for (int b = tid; b < NBUK; b += 256) hist[b] = 0;
    __syncthreads();

    int dArr[16], ranks[16];
#pragma unroll
    for (int k = 0; k < 16; ++k) {
        int i = tid + (k << 8);
        if (i < csize) {
            int d = ei[E + base + i];
            dArr[k]  = d;
            ranks[k] = atomicAdd(&hist[d >> 8], 1);
        }
    }
    __syncthreads();

    int IT = (NBUK + 255) >> 8;
    int b0 = tid * IT;
    int lsum = 0;
    for (int k = 0; k < IT; ++k) {
        int b = b0 + k;
        if (b < NBUK) lsum += hist[b];
    }
    int lane = tid & 63, wid = tid >> 6;
    int inc = lsum;
#pragma unroll
    for (int off = 1; off < 64; off <<= 1) {
        int t = __shfl_up(inc, off);
        if (lane >= off) inc += t;
    }
    if (lane == 63) wsum[wid] = inc;
    __syncthreads();
    if (tid == 0) {
        int acc = 0;
#pragma unroll
        for (int w = 0; w < 4; ++w) { int t = wsum[w]; wsum[w] = acc; acc += t; }
    }
    __syncthreads();
    int run = wsum[wid] + inc - lsum;
    for (int k = 0; k < IT; ++k) {
        int b = b0 + k;
        if (b < NBUK) { int h = hist[b]; hist[b] = run; run += h; }
    }
    __syncthreads();

#pragma unroll
    for (int k = 0; k < 16; ++k) {
        int i = tid + (k << 8);
        if (i < csize) {
            int gi = base + i;
            int d  = dArr[k];
            int b  = d >> 8;
            int s  = hist[b] + ranks[k];
            meta[s] = (unsigned)i | ((unsigned)b << 12) | ((unsigned)(d & 255) << 22);
            srcS[i] = ei[gi];
            __half2 uv = __floats2half2_rn(attr[2 * gi], attr[2 * gi + 1]);
            attrS[i] = *(const unsigned*)&uv;
        }
    }
    __syncthreads();

    for (int s = tid; s < csize; s += 256) {
        unsigned mt = meta[s];
        int i = mt & 4095;
        int b = (mt >> 12) & 1023;
        unsigned av = attrS[i];
        float2 uv = __half22float2(*(const __half2*)&av);
        uint4 rec = make_edge_rec((unsigned)srcS[i], uv.x, uv.y);
        int gpos = offs[b * nWG + wg] + (s - hist[b]);
        buf1[gpos] = rec;
        dl1[gpos]  = (unsigned char)(mt >> 22);
    }
}

// ---------------- Phase B: per-bucket exact-dst sort + rowptr ----------------

__global__ __launch_bounds__(256) void kB_sort(
    const uint4* __restrict__ buf1, const unsigned char* __restrict__ dl1,
    const int* __restrict__ off, int nWG, int NBUK, int N, int E,
    uint4* __restrict__ edges, int* __restrict__ rowptr) {
    __shared__ int hist[256], pref[256], curs[256];
    __shared__ int sbase, ssize;
    int b = blockIdx.x, tid = threadIdx.x;
    if (tid == 0) {
        int s  = off[b * nWG];
        int e2 = (b + 1 < NBUK) ? off[(b + 1) * nWG] : E;
        sbase = s; ssize = e2 - s;
    }
    hist[tid] = 0;
    __syncthreads();
    int base = sbase, size = ssize;
    for (int i = tid; i < size; i += 256) atomicAdd(&hist[dl1[base + i]], 1);
    __syncthreads();
    if (tid == 0) {
        int acc = 0;
        for (int j = 0; j < 256; ++j) { pref[j] = acc; acc += hist[j]; }
    }
    __syncthreads();
    curs[tid] = pref[tid];
    int node = b * 256 + tid;
    if (node < N) rowptr[node] = base + pref[tid];
    if (b == NBUK - 1 && tid == 0) rowptr[N] = E;
    __syncthreads();
    for (int i = tid; i < size; i += 256) {
        int p = atomicAdd(&curs[dl1[base + i]], 1);
        edges[base + p] = buf1[base + i];
    }
}

// ---------------- w2 + root2 pre-pack into B-fragment order (fp16) ----------------
// agg p = k*32 + ch  ->  K-step s contributes k=s, ch=(l>>4)*8+j.

__global__ void k_w2pack(const float* __restrict__ w2, const float* __restrict__ root2,
                         _Float16* __restrict__ w2f) {
    int f = blockIdx.x * blockDim.x + threadIdx.x;
    int stride = gridDim.x * blockDim.x;
    for (; f < 34816; f += stride) {
        int j = f & 7, l = (f >> 3) & 63, t = (f >> 9) & 3;
        int o = t * 16 + (l & 15);
        float v;
        if (f < 32768) {
            int s  = f >> 11;                     // K-step == basis k
            int ch = ((l >> 4) << 3) + j;         // 0..31
            v = w2[(s * 32 + ch) * 64 + o];
        } else {
            int ci = ((l >> 4) << 3) + j;
            v = root2[ci * 64 + o];
        }
        w2f[f] = (_Float16)v;
    }
}

// ---------------- fc1w pre-pack into B-fragment order (fp16) ----------------

__global__ void k_fcpack(const float* __restrict__ fc1w, _Float16* __restrict__ fc1wf) {
    int f = blockIdx.x * blockDim.x + threadIdx.x;
    if (f >= 8192) return;
    int j = f & 7, l = (f >> 3) & 63, t = (f >> 9) & 7, s = f >> 12;
    int k = s * 32 + ((l >> 4) << 3) + j;
    int o = t * 16 + (l & 15);
    fc1wf[f] = (_Float16)fc1w[k * 128 + o];
}

// ---------------- Layer 1 conv (in=1 -> out=32), thread per node, fp16 out ----------------

__global__ void k_conv1(const float* __restrict__ x, const int* __restrict__ rowptr,
                        const uint4* __restrict__ edges,
                        const float* __restrict__ w1, const float* __restrict__ root1,
                        const float* __restrict__ b1, _Float16* __restrict__ h1h, int N) {
    __shared__ float w1s[16 * 32];
    __shared__ float r1s[32], b1s[32];
    int tid = threadIdx.x;
    for (int i = tid; i < 512; i += blockDim.x) w1s[i] = w1[i];
    if (tid < 32) { r1s[tid] = root1[tid]; b1s[tid] = b1[tid]; }
    __syncthreads();
    int n = blockIdx.x * blockDim.x + tid;
    if (n >= N) return;
    float agg[16] = {};
    int s = rowptr[n], e = rowptr[n + 1];

#define P1(rec, xs) { \
    float bu[4], bv[4]; \
    unpack_basis(rec, bu, bv); \
    float t0 = (xs) * bv[0], t1 = (xs) * bv[1], t2 = (xs) * bv[2], t3 = (xs) * bv[3]; \
    agg[0]  += bu[0] * t0; agg[1]  += bu[1] * t0; agg[2]  += bu[2] * t0; agg[3]  += bu[3] * t0; \
    agg[4]  += bu[0] * t1; agg[5]  += bu[1] * t1; agg[6]  += bu[2] * t1; agg[7]  += bu[3] * t1; \
    agg[8]  += bu[0] * t2; agg[9]  += bu[1] * t2; agg[10] += bu[2] * t2; agg[11] += bu[3] * t2; \
    agg[12] += bu[0] * t3; agg[13] += bu[1] * t3; agg[14] += bu[2] * t3; agg[15] += bu[3] * t3; }

    int j = s;
    for (; j + 3 < e; j += 4) {
        uint4 r0 = edges[j], r1 = edges[j + 1], r2 = edges[j + 2], r3 = edges[j + 3];
        float x0 = x[r0.x], x1 = x[r1.x], x2 = x[r2.x], x3 = x[r3.x];
        P1(r0, x0); P1(r1, x1); P1(r2, x2); P1(r3, x3);
    }
    for (; j < e; ++j) {
        uint4 r = edges[j];
        float xs = x[r.x];
        P1(r, xs);
    }
#undef P1

    float xn = x[n];
    _Float16* hp = h1h + (size_t)n * 32;
#pragma unroll
    for (int o8 = 0; o8 < 4; ++o8) {
        half8 hv;
#pragma unroll
        for (int oo = 0; oo < 8; ++oo) {
            int o = o8 * 8 + oo;
            float acc = b1s[o] + xn * r1s[o];
#pragma unroll
            for (int k = 0; k < 16; ++k) acc += agg[k] * w1s[k * 32 + o];
            hv[oo] = (_Float16)acc;
        }
        *(half8*)(hp + o8 * 8) = hv;
    }
}

// ---------------- BatchNorm (fp16 input stats) ----------------

template <int C>
__global__ void k_bnstath(const _Float16* __restrict__ h, int N, double* __restrict__ sums) {
    __shared__ float sh1[C], sh2[C];
    int tid  = blockIdx.x * blockDim.x + threadIdx.x;
    int c    = tid & (C - 1);
    int row  = tid / C;
    int rstr = (gridDim.x * blockDim.x) / C;
    float s1 = 0.f, s2 = 0.f;
    for (int r = row; r < N; r += rstr) {
        float v = (float)h[(size_t)r * C + c];
        s1 += v; s2 += v * v;
    }
    if (threadIdx.x < C) { sh1[threadIdx.x] = 0.f; sh2[threadIdx.x] = 0.f; }
    __syncthreads();
    atomicAdd(&sh1[c], s1);
    atomicAdd(&sh2[c], s2);
    __syncthreads();
    if (threadIdx.x < C) {
        atomicAdd(&sums[threadIdx.x],     (double)sh1[threadIdx.x]);
        atomicAdd(&sums[C + threadIdx.x], (double)sh2[threadIdx.x]);
    }
}

__global__ void k_bnfinal(const double* __restrict__ sums, const float* __restrict__ gamma,
                          const float* __restrict__ beta, int C, int N, float* __restrict__ scsh) {
    int c = threadIdx.x;
    if (c < C) {
        double m   = sums[c] / (double)N;
        double var = sums[C + c] / (double)N - m * m;
        float vpe  = (float)var + 1e-5f;
        float sc   = gamma[c] / sqrtf(vpe);
        scsh[c]     = sc;
        scsh[C + c] = beta[c] - (float)m * sc;
    }
}

// BN + ELU for h1h (C=32), in place fp16
__global__ void k_bnelu32h(_Float16* __restrict__ hh, int N, const float* __restrict__ scsh) {
    int total = N * 4;
    int i = blockIdx.x * blockDim.x + threadIdx.x;
    int stride = gridDim.x * blockDim.x;
    for (; i < total; i += stride) {
        half8 v = *(half8*)(hh + (size_t)i * 8);
        int c0 = (i * 8) & 31;
        half8 r;
#pragma unroll
        for (int j = 0; j < 8; ++j)
            r[j] = (_Float16)eluf((float)v[j] * scsh[c0 + j] + scsh[32 + c0 + j]);
        *(half8*)(hh + (size_t)i * 8) = r;
    }
}

// ---------------- Layer 2 fused: MFMA aggregation + GEMM (k_ag2) ----------------
// C0 covers even channels (col m -> ch 2m), C1 odd. Gather = one uint/lane/edge.
// agg LDS: p = k*32 + ch, stored as uint (ch-pair); row stride 262 uints (1048B).

__global__ __launch_bounds__(256) void k_ag2(
    const _Float16* __restrict__ h1h, const int* __restrict__ rowptr,
    const uint4* __restrict__ edges, const _Float16* __restrict__ w2f,
    const float* __restrict__ b2, _Float16* __restrict__ out2h, int N) {
    __shared__ __align__(16) unsigned aggW[16][262];      // 16768 B
    __shared__ __align__(16) _Float16 basisL[4][16][76];  // 9728 B, stride 152B
    __shared__ __align__(16) int      srcL[4][64];
    int tid = threadIdx.x, l = tid & 63, w = tid >> 6;
    int g = l >> 4, m = l & 15;
    int n0 = blockIdx.x * 16;
    const unsigned* h32 = (const unsigned*)h1h;

    // ---- phase 1: aggregation ----
    for (int q = 0; q < 4; ++q) {
        int row = w * 4 + q;
        int n = n0 + row;
        if (n < N) {
            int s = __builtin_amdgcn_readfirstlane(rowptr[n]);
            int e = __builtin_amdgcn_readfirstlane(rowptr[n + 1]);
            f32x4 C0 = {0.f, 0.f, 0.f, 0.f}, C1 = C0;
            for (int t = s; t < e; t += 64) {
                int eg = t + l;
                bool act = eg < e;
                uint4 rec = edges[act ? eg : e - 1];
                srcL[w][l] = act ? (int)rec.x : 0;
                float bu[4], bv[4];
                unpack_basis(rec, bu, bv);
#pragma unroll
                for (int kv = 0; kv < 4; ++kv)
#pragma unroll
                    for (int ku = 0; ku < 4; ++ku)
                        basisL[w][kv * 4 + ku][l] = (_Float16)(bu[ku] * bv[kv]);
                int rem = e - t;
#pragma unroll
                for (int kh = 0; kh < 2; ++kh) {
                    if (kh == 1 && rem <= 32) break;
                    int ebase = kh * 32 + g * 8;
                    half4 alo = *(const half4*)&basisL[w][m][ebase];
                    half4 ahi = *(const half4*)&basisL[w][m][ebase + 4];
                    half8 a;
#pragma unroll
                    for (int i = 0; i < 4; ++i) { a[i] = alo[i]; a[4 + i] = ahi[i]; }
                    unsigned u[8];
#pragma unroll
                    for (int j = 0; j < 8; ++j) {
                        int sj = srcL[w][ebase + j];
                        bool aj = (t + ebase + j) < e;
                        unsigned uv = h32[(size_t)sj * 16 + m];   // ch 2m | 2m+1
                        u[j] = aj ? uv : 0u;
                    }
                    uintx4 p0, p1;
#pragma unroll
                    for (int tt = 0; tt < 4; ++tt) {
                        p0[tt] = (u[2 * tt] & 0xFFFFu) | (u[2 * tt + 1] << 16);
                        p1[tt] = (u[2 * tt] >> 16) | (u[2 * tt + 1] & 0xFFFF0000u);
                    }
                    half8 b0 = __builtin_bit_cast(half8, p0);
                    half8 b1 = __builtin_bit_cast(half8, p1);
                    C0 = __builtin_amdgcn_mfma_f32_16x16x32_f16(a, b0, C0, 0, 0, 0);
                    C1 = __builtin_amdgcn_mfma_f32_16x16x32_f16(a, b1, C1, 0, 0, 0);
                }
            }
            // D[row=k=g*4+r][col m] -> ch 2m (C0), 2m+1 (C1); p-pair uint at k*16+m
#pragma unroll
            for (int r = 0; r < 4; ++r) {
                __half2 hp = __floats2half2_rn(C0[r], C1[r]);
                aggW[row][(g * 4 + r) * 16 + m] = *(const unsigned*)&hp;
            }
        }
    }
    __syncthreads();

    // ---- phase 2: [16 nodes x 544] @ w2f -> out2h ----
    f32x4 acc = {0.f, 0.f, 0.f, 0.f};
#pragma unroll
    for (int s = 0; s < 16; ++s) {
        uintx2 a01 = *(const uintx2*)&aggW[m][s * 16 + g * 4];
        uintx2 a23 = *(const uintx2*)&aggW[m][s * 16 + g * 4 + 2];
        uintx4 av; av[0] = a01[0]; av[1] = a01[1]; av[2] = a23[0]; av[3] = a23[1];
        half8 a = __builtin_bit_cast(half8, av);
        half8 b = *(const half8*)&w2f[(size_t)(((s * 4 + w) * 64) + l) * 8];
        acc = __builtin_amdgcn_mfma_f32_16x16x32_f16(a, b, acc, 0, 0, 0);
    }
    {   // root term
        int nn = n0 + m; if (nn > N - 1) nn = N - 1;
        half8 a = *(const half8*)&h1h[(size_t)nn * 32 + g * 8];
        half8 b = *(const half8*)&w2f[(size_t)(((64 + w) * 64) + l) * 8];
        acc = __builtin_amdgcn_mfma_f32_16x16x32_f16(a, b, acc, 0, 0, 0);
    }
    int o = w * 16 + m;
    float bb = b2[o];
#pragma unroll
    for (int r = 0; r < 4; ++r) {
        int node = n0 + g * 4 + r;
        if (node < N) out2h[(size_t)node * 64 + o] = (_Float16)(acc[r] + bb);
    }
}

// ---------------- Final MLP via MFMA ----------------

__global__ __launch_bounds__(256) void k_fcm(
    const _Float16* __restrict__ out2h, const _Float16* __restrict__ fc1wf,
    const float* __restrict__ scsh, const float* __restrict__ fc1b,
    const float* __restrict__ fc2w, const float* __restrict__ fc2b,
    float* __restrict__ out, int N, int ntiles) {
    __shared__ _Float16 fw[8192];
    __shared__ float scs[64], shs[64], b1s[128], w2sv[128];
    int tid = threadIdx.x;
    {
        const uint4* s4 = (const uint4*)fc1wf;
        uint4* d4 = (uint4*)fw;
        for (int i = tid; i < 1024; i += 256) d4[i] = s4[i];
    }
    if (tid < 128) { b1s[tid] = fc1b[tid]; w2sv[tid] = fc2w[tid]; }
    if (tid < 64)  { scs[tid] = scsh[tid]; shs[tid] = scsh[64 + tid]; }
    __syncthreads();
    const half8* bp = (const half8*)fw;
    int l = tid & 63, w = tid >> 6;
    int g = l >> 4, m = l & 15, klo = g * 8;
    float f2b = fc2b[0];
    for (int tile = blockIdx.x * 4 + w; tile < ntiles; tile += gridDim.x * 4) {
        int base = tile * 16;
        int arow = base + m; if (arow > N - 1) arow = N - 1;
        const half8* hp = (const half8*)(out2h + (size_t)arow * 64 + klo);
        half8 r0 = hp[0];
        half8 r1 = hp[4];
        half8 a0, a1;
#pragma unroll
        for (int j = 0; j < 8; ++j) {
            int c0 = klo + j, c1 = 32 + klo + j;
            a0[j] = (_Float16)eluf((float)r0[j] * scs[c0] + shs[c0]);
            a1[j] = (_Float16)eluf((float)r1[j] * scs[c1] + shs[c1]);
        }
        f32x4 acc[8];
#pragma unroll
        for (int t = 0; t < 8; ++t) {
            f32x4 z = {0.f, 0.f, 0.f, 0.f};
            acc[t] = __builtin_amdgcn_mfma_f32_16x16x32_f16(a0, bp[t * 64 + l], z, 0, 0, 0);
            acc[t] = __builtin_amdgcn_mfma_f32_16x16x32_f16(a1, bp[(8 + t) * 64 + l], acc[t], 0, 0, 0);
        }
#pragma unroll
        for (int r = 0; r < 4; ++r) {
            float sum = 0.f;
#pragma unroll
            for (int t = 0; t < 8; ++t) {
                int o = t * 16 + m;
                sum += eluf(acc[t][r] + b1s[o]) * w2sv[o];
            }
            sum += __shfl_xor(sum, 1);
            sum += __shfl_xor(sum, 2);
            sum += __shfl_xor(sum, 4);
            sum += __shfl_xor(sum, 8);
            int node = base + g * 4 + r;
            if (m == 0 && node < N) out[node] = sum + f2b;
        }
    }
}

// ---------------------------------------------------------------------------

extern "C" void kernel_launch(void* const* d_in, const int* in_sizes, int n_in,
                              void* d_out, int out_size, void* d_ws, size_t ws_size,
                              hipStream_t stream) {
    const float* x     = (const float*)d_in[0];
    const int*   ei    = (const int*)  d_in[1];
    const float* attr  = (const float*)d_in[2];
    const float* w1    = (const float*)d_in[3];
    const float* root1 = (const float*)d_in[4];
    const float* b1    = (const float*)d_in[5];
    const float* g1    = (const float*)d_in[6];
    const float* be1   = (const float*)d_in[7];
    const float* w2    = (const float*)d_in[8];
    const float* root2 = (const float*)d_in[9];
    const float* b2    = (const float*)d_in[10];
    const float* g2    = (const float*)d_in[11];
    const float* be2   = (const float*)d_in[12];
    const float* fc1w  = (const float*)d_in[13];
    const float* fc1b  = (const float*)d_in[14];
    const float* fc2w  = (const float*)d_in[15];
    const float* fc2b  = (const float*)d_in[16];
    float* out = (float*)d_out;

    int N = in_sizes[0];          // 150000
    int E = in_sizes[1] / 2;      // 3000000

    int nWG  = (E + ACHUNK - 1) / ACHUNK;   // 733
    int NBUK = (N + 255) >> 8;              // 586
    int M    = NBUK * nWG;                  // ~430k

    char* ws = (char*)d_ws;
    size_t off = 0;
    auto alloc = [&](size_t bytes) -> void* {
        void* p = ws + off;
        off = (off + bytes + 255) & ~(size_t)255;
        return p;
    };
    int*      rowptr    = (int*)     alloc((size_t)(N + 1) * 4);
    int*      blockSums = (int*)     alloc(1024 * 4);
    int*      blockOff  = (int*)     alloc(1024 * 4);
    double*   bnsum1    = (double*)  alloc(128 * 8);
    double*   bnsum2    = (double*)  alloc(128 * 8);
    float*    scsh1     = (float*)   alloc(64 * 4);
    float*    scsh2     = (float*)   alloc(128 * 4);
    _Float16* w2f       = (_Float16*)alloc(34816 * 2);
    _Float16* fc1wf     = (_Float16*)alloc(8192 * 2);
    int*      cnt       = (int*)     alloc((size_t)M * 4);
    int*      offs      = (int*)     alloc((size_t)M * 4);
    uint4*    edges     = (uint4*)   alloc((size_t)E * 16);
    size_t    Roff      = off;              // start of aliasable region
    _Float16* h1h       = (_Float16*)alloc((size_t)N * 32 * 2);   //  9.6 MB
    _Float16* out2h     = (_Float16*)alloc((size_t)N * 64 * 2);   // 19.2 MB
    // buf1 + dl1 alias [h1h|out2h|free space]; dead before conv1 runs
    uint4*         buf1 = (uint4*)(ws + Roff);
    unsigned char* dl1  = (unsigned char*)(ws + Roff + (size_t)E * 16);
    (void)n_in; (void)out_size; (void)ws_size;

    hipMemsetAsync(bnsum1, 0, 128 * 8, stream);
    hipMemsetAsync(bnsum2, 0, 128 * 8, stream);

    size_t ldsA1 = (size_t)NBUK * 4;
    size_t ldsA2 = (size_t)NBUK * 4 + (size_t)ACHUNK * 12;
    int NBs = (M + 1023) / 1024;            // ~420 <= 512

    k_w2pack<<<136, 256, 0, stream>>>(w2, root2, w2f);
    k_fcpack<<<32, 256, 0, stream>>>(fc1w, fc1wf);
    kA1_hist<<<nWG, 256, ldsA1, stream>>>(ei + E, E, cnt, nWG, NBUK);
    k_scan1<<<NBs, 256, 0, stream>>>(cnt, M, offs, blockSums);
    k_scan2<<<1, 256, 0, stream>>>(blockSums, NBs, blockOff);
    k_scan3b<<<(M + 255) / 256, 256, 0, stream>>>(offs, blockOff, M);
    kA2_fill<<<nWG, 256, ldsA2, stream>>>(ei, attr, E, offs, nWG, NBUK, buf1, dl1);
    kB_sort<<<NBUK, 256, 0, stream>>>(buf1, dl1, offs, nWG, NBUK, N, E, edges, rowptr);

    k_conv1<<<(N + 255) / 256, 256, 0, stream>>>(x, rowptr, edges, w1, root1, b1, h1h, N);
    k_bnstath<32><<<256, 256, 0, stream>>>(h1h, N, bnsum1);
    k_bnfinal<<<1, 64, 0, stream>>>(bnsum1, g1, be1, 32, N, scsh1);
    k_bnelu32h<<<1024, 256, 0, stream>>>(h1h, N, scsh1);

    k_ag2<<<(N + 15) / 16, 256, 0, stream>>>(h1h, rowptr, edges, w2f, b2, out2h, N);

    k_bnstath<64><<<256, 256, 0, stream>>>(out2h, N, bnsum2);
    k_bnfinal<<<1, 64, 0, stream>>>(bnsum2, g2, be2, 64, N, scsh2);

    int ntilesF = (N + 15) / 16;
    int gridF = (ntilesF + 3) / 4; if (gridF > 2344) gridF = 2344;
    k_fcm<<<gridF, 256, 0, stream>>>(out2h, fc1wf, scsh2, fc1b, fc2w, fc2b, out, N, ntilesF);
}

// Round 12
// 311.316 us; speedup vs baseline: 1.0296x; 1.0296x over previous
//
#include <hip/hip_runtime.h>
#include <hip/hip_fp16.h>
#include <math.h>

// ---------------------------------------------------------------------------
// SplineCNN (K=4, dim=2, deg=2). v12: 8-byte edge records (fp16 u,v + src +
// dlow packed in uint2), basis recomputed at consumers; dl1 eliminated.
// Fused MFMA agg+GEMM (k_ag2, v11 structure); MFMA final MLP.
// ---------------------------------------------------------------------------

typedef _Float16 half8 __attribute__((ext_vector_type(8)));
typedef _Float16 half4 __attribute__((ext_vector_type(4)));
typedef float    f32x4 __attribute__((ext_vector_type(4)));
typedef unsigned uintx2 __attribute__((ext_vector_type(2)));
typedef unsigned uintx4 __attribute__((ext_vector_type(4)));

#define ACHUNK 4096   // edges per partition WG (16 per thread)

__device__ __forceinline__ void bspline4(float a, float B[4]) {
    a = fminf(fmaxf(a, 0.f), 1.f);
    float v  = a * 2.0f;          // K - DEG = 2
    float kv = floorf(v);
    float t  = v - kv;
    int   ik = (int)kv;           // 0..2
    float b0 = 0.5f * (1.f - t) * (1.f - t);
    float b1 = (t - t * t) + 0.5f;
    float b2 = 0.5f * t * t;
    int c0 = ik;
    int c1 = ik + 1;
    int c2 = ik + 2; if (c2 > 3) c2 = 3;
#pragma unroll
    for (int j = 0; j < 4; ++j)
        B[j] = (c0 == j ? b0 : 0.f) + (c1 == j ? b1 : 0.f) + (c2 == j ? b2 : 0.f);
}

__device__ __forceinline__ float eluf(float x) {
    return x > 0.f ? x : expm1f(x);
}

// 8B record: x = u(fp16) | v(fp16)<<16 ; y = src(18b) | dlow(8b)<<18
__device__ __forceinline__ void decode_edge8(uint2 rec, int& src,
                                             float bu[4], float bv[4]) {
    src = (int)(rec.x & 0u, rec.y & 0x3FFFFu);
    float2 uv = __half22float2(*(const __half2*)&rec.x);
    bspline4(uv.x, bu);
    bspline4(uv.y, bv);
}

// ---------------- Phase A: bucketed partition (bucket = dst >> 8) ----------------

__global__ void kA1_hist(const int* __restrict__ dst, int E, int* __restrict__ cnt,
                         int nWG, int NBUK) {
    extern __shared__ int hist[];   // NBUK ints
    int wg = blockIdx.x, tid = threadIdx.x;
    for (int b = tid; b < NBUK; b += 256) hist[b] = 0;
    __syncthreads();
    int base = wg * ACHUNK;
    int end  = base + ACHUNK; if (end > E) end = E;
    for (int i = base + tid; i < end; i += 256)
        atomicAdd(&hist[dst[i] >> 8], 1);
    __syncthreads();
    for (int b = tid; b < NBUK; b += 256) cnt[b * nWG + wg] = hist[b];
}

__global__ void k_scan1(const int* __restrict__ in, int M,
                        int* __restrict__ outp, int* __restrict__ blockSums) {
    __shared__ int wsum[4];
    int tid  = threadIdx.x;
    int base = blockIdx.x * 1024 + tid * 4;
    int d0 = (base + 0) < M ? in[base + 0] : 0;
    int d1 = (base + 1) < M ? in[base + 1] : 0;
    int d2 = (base + 2) < M ? in[base + 2] : 0;
    int d3 = (base + 3) < M ? in[base + 3] : 0;
    int s4 = d0 + d1 + d2 + d3;
    int lane = tid & 63, wid = tid >> 6;
    int inc = s4;
#pragma unroll
    for (int off = 1; off < 64; off <<= 1) {
        int t = __shfl_up(inc, off);
        if (lane >= off) inc += t;
    }
    if (lane == 63) wsum[wid] = inc;
    __syncthreads();
    if (tid == 0) {
        int acc = 0;
#pragma unroll
        for (int w = 0; w < 4; ++w) { int t = wsum[w]; wsum[w] = acc; acc += t; }
    }
    __syncthreads();
    int ebase = wsum[wid] + inc - s4;
    if ((base + 0) < M) outp[base + 0] = ebase;
    if ((base + 1) < M) outp[base + 1] = ebase + d0;
    if ((base + 2) < M) outp[base + 2] = ebase + d0 + d1;
    if ((base + 3) < M) outp[base + 3] = ebase + d0 + d1 + d2;
    if (tid == 255) blockSums[blockIdx.x] = ebase + s4;
}

// capacity 512 (2 elems per thread)
__global__ void k_scan2(const int* __restrict__ blockSums, int NB, int* __restrict__ blockOff) {
    __shared__ int sh[256];
    int tid = threadIdx.x;
    int i0 = 2 * tid, i1 = 2 * tid + 1;
    int a = (i0 < NB) ? blockSums[i0] : 0;
    int b = (i1 < NB) ? blockSums[i1] : 0;
    int p = a + b;
    sh[tid] = p;
    __syncthreads();
    for (int off = 1; off < 256; off <<= 1) {
        int v = (tid >= off) ? sh[tid - off] : 0;
        __syncthreads();
        sh[tid] += v;
        __syncthreads();
    }
    int excl = sh[tid] - p;
    if (i0 < NB) blockOff[i0] = excl;
    if (i1 < NB) blockOff[i1] = excl + a;
}

__global__ void k_scan3b(int* __restrict__ arr, const int* __restrict__ blockOff, int M) {
    int i = blockIdx.x * blockDim.x + threadIdx.x;
    if (i < M) arr[i] += blockOff[i >> 10];
}

// fill pass: whole chunk staged in LDS; reads coalesced-once, writes runs of 8B recs.
__global__ __launch_bounds__(256) void kA2_fill(
    const int* __restrict__ ei, const float* __restrict__ attr, int E,
    const int* __restrict__ offs, int nWG, int NBUK,
    uint2* __restrict__ buf1) {
    extern __shared__ int lds[];
    int*      hist  = lds;                         // NBUK (becomes pref)
    unsigned* recB  = (unsigned*)(hist + NBUK);    // ACHUNK: src|dlow<<18
    unsigned* attrS = recB + ACHUNK;               // ACHUNK: fp16 u|v
    unsigned* meta  = attrS + ACHUNK;              // ACHUNK: i | b<<12
    __shared__ int wsum[4];
    int wg = blockIdx.x, tid = threadIdx.x;
    int base  = wg * ACHUNK;
    int csize = E - base; if (csize > ACHUNK) csize = ACHUNK;

    for (int b = tid; b < NBUK; b += 256) hist[b] = 0;
    __syncthreads();

    int dArr[16], ranks[16];
#pragma unroll
    for (int k = 0; k < 16; ++k) {
        int i = tid + (k << 8);
        if (i < csize) {
            int d = ei[E + base + i];
            dArr[k]  = d;
            ranks[k] = atomicAdd(&hist[d >> 8], 1);
        }
    }
    __syncthreads();

    int IT = (NBUK + 255) >> 8;
    int b0 = tid * IT;
    int lsum = 0;
    for (int k = 0; k < IT; ++k) {
        int b = b0 + k;
        if (b < NBUK) lsum += hist[b];
    }
    int lane = tid & 63, wid = tid >> 6;
    int inc = lsum;
#pragma unroll
    for (int off = 1; off < 64; off <<= 1) {
        int t = __shfl_up(inc, off);
        if (lane >= off) inc += t;
    }
    if (lane == 63) wsum[wid] = inc;
    __syncthreads();
    if (tid == 0) {
        int acc = 0;
#pragma unroll
        for (int w = 0; w < 4; ++w) { int t = wsum[w]; wsum[w] = acc; acc += t; }
    }
    __syncthreads();
    int run = wsum[wid] + inc - lsum;
    for (int k = 0; k < IT; ++k) {
        int b = b0 + k;
        if (b < NBUK) { int h = hist[b]; hist[b] = run; run += h; }
    }
    __syncthreads();   // hist[] now = pref[]

#pragma unroll
    for (int k = 0; k < 16; ++k) {
        int i = tid + (k << 8);
        if (i < csize) {
            int gi = base + i;
            int d  = dArr[k];
            int b  = d >> 8;
            int s  = hist[b] + ranks[k];
            meta[s] = (unsigned)i | ((unsigned)b << 12);
            recB[i] = (unsigned)ei[gi] | ((unsigned)(d & 255) << 18);
            __half2 uv = __floats2half2_rn(attr[2 * gi], attr[2 * gi + 1]);
            attrS[i] = *(const unsigned*)&uv;
        }
    }
    __syncthreads();

    for (int s = tid; s < csize; s += 256) {
        unsigned mt = meta[s];
        int i = mt & 4095;
        int b = mt >> 12;
        uint2 rec;
        rec.x = attrS[i];
        rec.y = recB[i];
        int gpos = offs[b * nWG + wg] + (s - hist[b]);
        buf1[gpos] = rec;
    }
}

// ---------------- Phase B: per-bucket exact-dst sort + rowptr ----------------

__global__ __launch_bounds__(256) void kB_sort(
    const uint2* __restrict__ buf1,
    const int* __restrict__ off, int nWG, int NBUK, int N, int E,
    uint2* __restrict__ edges, int* __restrict__ rowptr) {
    __shared__ int hist[256], pref[256], curs[256];
    __shared__ int sbase, ssize;
    int b = blockIdx.x, tid = threadIdx.x;
    if (tid == 0) {
        int s  = off[b * nWG];
        int e2 = (b + 1 < NBUK) ? off[(b + 1) * nWG] : E;
        sbase = s; ssize = e2 - s;
    }
    hist[tid] = 0;
    __syncthreads();
    int base = sbase, size = ssize;
    for (int i = tid; i < size; i += 256)
        atomicAdd(&hist[(buf1[base + i].y >> 18) & 255], 1);
    __syncthreads();
    if (tid == 0) {
        int acc = 0;
        for (int j = 0; j < 256; ++j) { pref[j] = acc; acc += hist[j]; }
    }
    __syncthreads();
    curs[tid] = pref[tid];
    int node = b * 256 + tid;
    if (node < N) rowptr[node] = base + pref[tid];
    if (b == NBUK - 1 && tid == 0) rowptr[N] = E;
    __syncthreads();
    for (int i = tid; i < size; i += 256) {
        uint2 rec = buf1[base + i];
        int p = atomicAdd(&curs[(rec.y >> 18) & 255], 1);
        edges[base + p] = rec;
    }
}

// ---------------- w2 + root2 pre-pack into B-fragment order (fp16) ----------------
// agg p = k*32 + ch  ->  K-step s contributes k=s, ch=(l>>4)*8+j.

__global__ void k_w2pack(const float* __restrict__ w2, const float* __restrict__ root2,
                         _Float16* __restrict__ w2f) {
    int f = blockIdx.x * blockDim.x + threadIdx.x;
    int stride = gridDim.x * blockDim.x;
    for (; f < 34816; f += stride) {
        int j = f & 7, l = (f >> 3) & 63, t = (f >> 9) & 3;
        int o = t * 16 + (l & 15);
        float v;
        if (f < 32768) {
            int s  = f >> 11;                     // K-step == basis k
            int ch = ((l >> 4) << 3) + j;         // 0..31
            v = w2[(s * 32 + ch) * 64 + o];
        } else {
            int ci = ((l >> 4) << 3) + j;
            v = root2[ci * 64 + o];
        }
        w2f[f] = (_Float16)v;
    }
}

// ---------------- fc1w pre-pack into B-fragment order (fp16) ----------------

__global__ void k_fcpack(const float* __restrict__ fc1w, _Float16* __restrict__ fc1wf) {
    int f = blockIdx.x * blockDim.x + threadIdx.x;
    if (f >= 8192) return;
    int j = f & 7, l = (f >> 3) & 63, t = (f >> 9) & 7, s = f >> 12;
    int k = s * 32 + ((l >> 4) << 3) + j;
    int o = t * 16 + (l & 15);
    fc1wf[f] = (_Float16)fc1w[k * 128 + o];
}

// ---------------- Layer 1 conv (in=1 -> out=32), thread per node, fp16 out ----------------

__global__ void k_conv1(const float* __restrict__ x, const int* __restrict__ rowptr,
                        const uint2* __restrict__ edges,
                        const float* __restrict__ w1, const float* __restrict__ root1,
                        const float* __restrict__ b1, _Float16* __restrict__ h1h, int N) {
    __shared__ float w1s[16 * 32];
    __shared__ float r1s[32], b1s[32];
    int tid = threadIdx.x;
    for (int i = tid; i < 512; i += blockDim.x) w1s[i] = w1[i];
    if (tid < 32) { r1s[tid] = root1[tid]; b1s[tid] = b1[tid]; }
    __syncthreads();
    int n = blockIdx.x * blockDim.x + tid;
    if (n >= N) return;
    float agg[16] = {};
    int s = rowptr[n], e = rowptr[n + 1];

#define P1(rec, xs) { \
    float2 uv = __half22float2(*(const __half2*)&rec.x); \
    float bu[4], bv[4]; \
    bspline4(uv.x, bu); bspline4(uv.y, bv); \
    float t0 = (xs) * bv[0], t1 = (xs) * bv[1], t2 = (xs) * bv[2], t3 = (xs) * bv[3]; \
    agg[0]  += bu[0] * t0; agg[1]  += bu[1] * t0; agg[2]  += bu[2] * t0; agg[3]  += bu[3] * t0; \
    agg[4]  += bu[0] * t1; agg[5]  += bu[1] * t1; agg[6]  += bu[2] * t1; agg[7]  += bu[3] * t1; \
    agg[8]  += bu[0] * t2; agg[9]  += bu[1] * t2; agg[10] += bu[2] * t2; agg[11] += bu[3] * t2; \
    agg[12] += bu[0] * t3; agg[13] += bu[1] * t3; agg[14] += bu[2] * t3; agg[15] += bu[3] * t3; }

    int j = s;
    for (; j + 3 < e; j += 4) {
        uint2 r0 = edges[j], r1 = edges[j + 1], r2 = edges[j + 2], r3 = edges[j + 3];
        float x0 = x[r0.y & 0x3FFFF], x1 = x[r1.y & 0x3FFFF];
        float x2 = x[r2.y & 0x3FFFF], x3 = x[r3.y & 0x3FFFF];
        P1(r0, x0); P1(r1, x1); P1(r2, x2); P1(r3, x3);
    }
    for (; j < e; ++j) {
        uint2 r = edges[j];
        float xs = x[r.y & 0x3FFFF];
        P1(r, xs);
    }
#undef P1

    float xn = x[n];
    _Float16* hp = h1h + (size_t)n * 32;
#pragma unroll
    for (int o8 = 0; o8 < 4; ++o8) {
        half8 hv;
#pragma unroll
        for (int oo = 0; oo < 8; ++oo) {
            int o = o8 * 8 + oo;
            float acc = b1s[o] + xn * r1s[o];
#pragma unroll
            for (int k = 0; k < 16; ++k) acc += agg[k] * w1s[k * 32 + o];
            hv[oo] = (_Float16)acc;
        }
        *(half8*)(hp + o8 * 8) = hv;
    }
}

// ---------------- BatchNorm (fp16 input stats) ----------------

template <int C>
__global__ void k_bnstath(const _Float16* __restrict__ h, int N, double* __restrict__ sums) {
    __shared__ float sh1[C], sh2[C];
    int tid  = blockIdx.x * blockDim.x + threadIdx.x;
    int c    = tid & (C - 1);
    int row  = tid / C;
    int rstr = (gridDim.x * blockDim.x) / C;
    float s1 = 0.f, s2 = 0.f;
    for (int r = row; r < N; r += rstr) {
        float v = (float)h[(size_t)r * C + c];
        s1 += v; s2 += v * v;
    }
    if (threadIdx.x < C) { sh1[threadIdx.x] = 0.f; sh2[threadIdx.x] = 0.f; }
    __syncthreads();
    atomicAdd(&sh1[c], s1);
    atomicAdd(&sh2[c], s2);
    __syncthreads();
    if (threadIdx.x < C) {
        atomicAdd(&sums[threadIdx.x],     (double)sh1[threadIdx.x]);
        atomicAdd(&sums[C + threadIdx.x], (double)sh2[threadIdx.x]);
    }
}

__global__ void k_bnfinal(const double* __restrict__ sums, const float* __restrict__ gamma,
                          const float* __restrict__ beta, int C, int N, float* __restrict__ scsh) {
    int c = threadIdx.x;
    if (c < C) {
        double m   = sums[c] / (double)N;
        double var = sums[C + c] / (double)N - m * m;
        float vpe  = (float)var + 1e-5f;
        float sc   = gamma[c] / sqrtf(vpe);
        scsh[c]     = sc;
        scsh[C + c] = beta[c] - (float)m * sc;
    }
}

// BN + ELU for h1h (C=32), in place fp16
__global__ void k_bnelu32h(_Float16* __restrict__ hh, int N, const float* __restrict__ scsh) {
    int total = N * 4;
    int i = blockIdx.x * blockDim.x + threadIdx.x;
    int stride = gridDim.x * blockDim.x;
    for (; i < total; i += stride) {
        half8 v = *(half8*)(hh + (size_t)i * 8);
        int c0 = (i * 8) & 31;
        half8 r;
#pragma unroll
        for (int j = 0; j < 8; ++j)
            r[j] = (_Float16)eluf((float)v[j] * scsh[c0 + j] + scsh[32 + c0 + j]);
        *(half8*)(hh + (size_t)i * 8) = r;
    }
}

// ---------------- Layer 2 fused: MFMA aggregation + GEMM (k_ag2) ----------------
// C0 even channels, C1 odd; gather = one uint per lane per edge.
// agg LDS: p = k*32 + ch as uint ch-pairs; row stride 262 uints.

__global__ __launch_bounds__(256) void k_ag2(
    const _Float16* __restrict__ h1h, const int* __restrict__ rowptr,
    const uint2* __restrict__ edges, const _Float16* __restrict__ w2f,
    const float* __restrict__ b2, _Float16* __restrict__ out2h, int N) {
    __shared__ __align__(16) unsigned aggW[16][262];
    __shared__ __align__(16) _Float16 basisL[4][16][76];
    __shared__ __align__(16) int      srcL[4][64];
    int tid = threadIdx.x, l = tid & 63, w = tid >> 6;
    int g = l >> 4, m = l & 15;
    int n0 = blockIdx.x * 16;
    const unsigned* h32 = (const unsigned*)h1h;

    for (int q = 0; q < 4; ++q) {
        int row = w * 4 + q;
        int n = n0 + row;
        if (n < N) {
            int s = __builtin_amdgcn_readfirstlane(rowptr[n]);
            int e = __builtin_amdgcn_readfirstlane(rowptr[n + 1]);
            f32x4 C0 = {0.f, 0.f, 0.f, 0.f}, C1 = C0;
            for (int t = s; t < e; t += 64) {
                int eg = t + l;
                bool act = eg < e;
                uint2 rec = edges[act ? eg : e - 1];
                srcL[w][l] = act ? (int)(rec.y & 0x3FFFFu) : 0;
                float2 uvf = __half22float2(*(const __half2*)&rec.x);
                float bu[4], bv[4];
                bspline4(uvf.x, bu);
                bspline4(uvf.y, bv);
#pragma unroll
                for (int kv = 0; kv < 4; ++kv)
#pragma unroll
                    for (int ku = 0; ku < 4; ++ku)
                        basisL[w][kv * 4 + ku][l] = (_Float16)(bu[ku] * bv[kv]);
                int rem = e - t;
#pragma unroll
                for (int kh = 0; kh < 2; ++kh) {
                    if (kh == 1 && rem <= 32) break;
                    int ebase = kh * 32 + g * 8;
                    half4 alo = *(const half4*)&basisL[w][m][ebase];
                    half4 ahi = *(const half4*)&basisL[w][m][ebase + 4];
                    half8 a;
#pragma unroll
                    for (int i = 0; i < 4; ++i) { a[i] = alo[i]; a[4 + i] = ahi[i]; }
                    unsigned u[8];
#pragma unroll
                    for (int j = 0; j < 8; ++j) {
                        int sj = srcL[w][ebase + j];
                        bool aj = (t + ebase + j) < e;
                        unsigned uv = h32[(size_t)sj * 16 + m];
                        u[j] = aj ? uv : 0u;
                    }
                    uintx4 p0, p1;
#pragma unroll
                    for (int tt = 0; tt < 4; ++tt) {
                        p0[tt] = (u[2 * tt] & 0xFFFFu) | (u[2 * tt + 1] << 16);
                        p1[tt] = (u[2 * tt] >> 16) | (u[2 * tt + 1] & 0xFFFF0000u);
                    }
                    half8 b0 = __builtin_bit_cast(half8, p0);
                    half8 b1 = __builtin_bit_cast(half8, p1);
                    C0 = __builtin_amdgcn_mfma_f32_16x16x32_f16(a, b0, C0, 0, 0, 0);
                    C1 = __builtin_amdgcn_mfma_f32_16x16x32_f16(a, b1, C1, 0, 0, 0);
                }
            }
#pragma unroll
            for (int r = 0; r < 4; ++r) {
                __half2 hp = __floats2half2_rn(C0[r], C1[r]);
                aggW[row][(g * 4 + r) * 16 + m] = *(const unsigned*)&hp;
            }
        }
    }
    __syncthreads();

    f32x4 acc = {0.f, 0.f, 0.f, 0.f};
#pragma unroll
    for (int s = 0; s < 16; ++s) {
        uintx2 a01 = *(const uintx2*)&aggW[m][s * 16 + g * 4];
        uintx2 a23 = *(const uintx2*)&aggW[m][s * 16 + g * 4 + 2];
        uintx4 av; av[0] = a01[0]; av[1] = a01[1]; av[2] = a23[0]; av[3] = a23[1];
        half8 a = __builtin_bit_cast(half8, av);
        half8 b = *(const half8*)&w2f[(size_t)(((s * 4 + w) * 64) + l) * 8];
        acc = __builtin_amdgcn_mfma_f32_16x16x32_f16(a, b, acc, 0, 0, 0);
    }
    {
        int nn = n0 + m; if (nn > N - 1) nn = N - 1;
        half8 a = *(const half8*)&h1h[(size_t)nn * 32 + g * 8];
        half8 b = *(const half8*)&w2f[(size_t)(((64 + w) * 64) + l) * 8];
        acc = __builtin_amdgcn_mfma_f32_16x16x32_f16(a, b, acc, 0, 0, 0);
    }
    int o = w * 16 + m;
    float bb = b2[o];
#pragma unroll
    for (int r = 0; r < 4; ++r) {
        int node = n0 + g * 4 + r;
        if (node < N) out2h[(size_t)node * 64 + o] = (_Float16)(acc[r] + bb);
    }
}

// ---------------- Final MLP via MFMA ----------------

__global__ __launch_bounds__(256) void k_fcm(
    const _Float16* __restrict__ out2h, const _Float16* __restrict__ fc1wf,
    const float* __restrict__ scsh, const float* __restrict__ fc1b,
    const float* __restrict__ fc2w, const float* __restrict__ fc2b,
    float* __restrict__ out, int N, int ntiles) {
    __shared__ _Float16 fw[8192];
    __shared__ float scs[64], shs[64], b1s[128], w2sv[128];
    int tid = threadIdx.x;
    {
        const uint4* s4 = (const uint4*)fc1wf;
        uint4* d4 = (uint4*)fw;
        for (int i = tid; i < 1024; i += 256) d4[i] = s4[i];
    }
    if (tid < 128) { b1s[tid] = fc1b[tid]; w2sv[tid] = fc2w[tid]; }
    if (tid < 64)  { scs[tid] = scsh[tid]; shs[tid] = scsh[64 + tid]; }
    __syncthreads();
    const half8* bp = (const half8*)fw;
    int l = tid & 63, w = tid >> 6;
    int g = l >> 4, m = l & 15, klo = g * 8;
    float f2b = fc2b[0];
    for (int tile = blockIdx.x * 4 + w; tile < ntiles; tile += gridDim.x * 4) {
        int base = tile * 16;
        int arow = base + m; if (arow > N - 1) arow = N - 1;
        const half8* hp = (const half8*)(out2h + (size_t)arow * 64 + klo);
        half8 r0 = hp[0];
        half8 r1 = hp[4];
        half8 a0, a1;
#pragma unroll
        for (int j = 0; j < 8; ++j) {
            int c0 = klo + j, c1 = 32 + klo + j;
            a0[j] = (_Float16)eluf((float)r0[j] * scs[c0] + shs[c0]);
            a1[j] = (_Float16)eluf((float)r1[j] * scs[c1] + shs[c1]);
        }
        f32x4 acc[8];
#pragma unroll
        for (int t = 0; t < 8; ++t) {
            f32x4 z = {0.f, 0.f, 0.f, 0.f};
            acc[t] = __builtin_amdgcn_mfma_f32_16x16x32_f16(a0, bp[t * 64 + l], z, 0, 0, 0);
            acc[t] = __builtin_amdgcn_mfma_f32_16x16x32_f16(a1, bp[(8 + t) * 64 + l], acc[t], 0, 0, 0);
        }
#pragma unroll
        for (int r = 0; r < 4; ++r) {
            float sum = 0.f;
#pragma unroll
            for (int t = 0; t < 8; ++t) {
                int o = t * 16 + m;
                sum += eluf(acc[t][r] + b1s[o]) * w2sv[o];
            }
            sum += __shfl_xor(sum, 1);
            sum += __shfl_xor(sum, 2);
            sum += __shfl_xor(sum, 4);
            sum += __shfl_xor(sum, 8);
            int node = base + g * 4 + r;
            if (m == 0 && node < N) out[node] = sum + f2b;
        }
    }
}

// ---------------------------------------------------------------------------

extern "C" void kernel_launch(void* const* d_in, const int* in_sizes, int n_in,
                              void* d_out, int out_size, void* d_ws, size_t ws_size,
                              hipStream_t stream) {
    const float* x     = (const float*)d_in[0];
    const int*   ei    = (const int*)  d_in[1];
    const float* attr  = (const float*)d_in[2];
    const float* w1    = (const float*)d_in[3];
    const float* root1 = (const float*)d_in[4];
    const float* b1    = (const float*)d_in[5];
    const float* g1    = (const float*)d_in[6];
    const float* be1   = (const float*)d_in[7];
    const float* w2    = (const float*)d_in[8];
    const float* root2 = (const float*)d_in[9];
    const float* b2    = (const float*)d_in[10];
    const float* g2    = (const float*)d_in[11];
    const float* be2   = (const float*)d_in[12];
    const float* fc1w  = (const float*)d_in[13];
    const float* fc1b  = (const float*)d_in[14];
    const float* fc2w  = (const float*)d_in[15];
    const float* fc2b  = (const float*)d_in[16];
    float* out = (float*)d_out;

    int N = in_sizes[0];          // 150000
    int E = in_sizes[1] / 2;      // 3000000

    int nWG  = (E + ACHUNK - 1) / ACHUNK;   // 733
    int NBUK = (N + 255) >> 8;              // 586
    int M    = NBUK * nWG;                  // ~430k

    char* ws = (char*)d_ws;
    size_t off = 0;
    auto alloc = [&](size_t bytes) -> void* {
        void* p = ws + off;
        off = (off + bytes + 255) & ~(size_t)255;
        return p;
    };
    int*      rowptr    = (int*)     alloc((size_t)(N + 1) * 4);
    int*      blockSums = (int*)     alloc(1024 * 4);
    int*      blockOff  = (int*)     alloc(1024 * 4);
    double*   bnsum1    = (double*)  alloc(128 * 8);
    double*   bnsum2    = (double*)  alloc(128 * 8);
    float*    scsh1     = (float*)   alloc(64 * 4);
    float*    scsh2     = (float*)   alloc(128 * 4);
    _Float16* w2f       = (_Float16*)alloc(34816 * 2);
    _Float16* fc1wf     = (_Float16*)alloc(8192 * 2);
    int*      cnt       = (int*)     alloc((size_t)M * 4);
    int*      offs      = (int*)     alloc((size_t)M * 4);
    uint2*    edges     = (uint2*)   alloc((size_t)E * 8);        // 24 MB
    size_t    Roff      = off;              // start of aliasable region
    _Float16* h1h       = (_Float16*)alloc((size_t)N * 32 * 2);   //  9.6 MB
    _Float16* out2h     = (_Float16*)alloc((size_t)N * 64 * 2);   // 19.2 MB
    // buf1 aliases [h1h|out2h] (24 MB <= 28.8 MB); dead before conv1 runs
    uint2* buf1 = (uint2*)(ws + Roff);
    (void)n_in; (void)out_size; (void)ws_size;

    hipMemsetAsync(bnsum1, 0, 128 * 8, stream);
    hipMemsetAsync(bnsum2, 0, 128 * 8, stream);

    size_t ldsA1 = (size_t)NBUK * 4;
    size_t ldsA2 = (size_t)NBUK * 4 + (size_t)ACHUNK * 12;
    int NBs = (M + 1023) / 1024;            // ~420 <= 512

    k_w2pack<<<136, 256, 0, stream>>>(w2, root2, w2f);
    k_fcpack<<<32, 256, 0, stream>>>(fc1w, fc1wf);
    kA1_hist<<<nWG, 256, ldsA1, stream>>>(ei + E, E, cnt, nWG, NBUK);
    k_scan1<<<NBs, 256, 0, stream>>>(cnt, M, offs, blockSums);
    k_scan2<<<1, 256, 0, stream>>>(blockSums, NBs, blockOff);
    k_scan3b<<<(M + 255) / 256, 256, 0, stream>>>(offs, blockOff, M);
    kA2_fill<<<nWG, 256, ldsA2, stream>>>(ei, attr, E, offs, nWG, NBUK, buf1);
    kB_sort<<<NBUK, 256, 0, stream>>>(buf1, offs, nWG, NBUK, N, E, edges, rowptr);

    k_conv1<<<(N + 255) / 256, 256, 0, stream>>>(x, rowptr, edges, w1, root1, b1, h1h, N);
    k_bnstath<32><<<256, 256, 0, stream>>>(h1h, N, bnsum1);
    k_bnfinal<<<1, 64, 0, stream>>>(bnsum1, g1, be1, 32, N, scsh1);
    k_bnelu32h<<<1024, 256, 0, stream>>>(h1h, N, scsh1);

    k_ag2<<<(N + 15) / 16, 256, 0, stream>>>(h1h, rowptr, edges, w2f, b2, out2h, N);

    k_bnstath<64><<<256, 256, 0, stream>>>(out2h, N, bnsum2);
    k_bnfinal<<<1, 64, 0, stream>>>(bnsum2, g2, be2, 64, N, scsh2);

    int ntilesF = (N + 15) / 16;
    int gridF = (ntilesF + 3) / 4; if (gridF > 2344) gridF = 2344;
    k_fcm<<<gridF, 256, 0, stream>>>(out2h, fc1wf, scsh2, fc1b, fc2w, fc2b, out, N, ntilesF);
}

// Round 13
// 305.565 us; speedup vs baseline: 1.0490x; 1.0188x over previous
//
#include <hip/hip_runtime.h>
#include <hip/hip_fp16.h>
#include <math.h>

// ---------------------------------------------------------------------------
// SplineCNN (K=4, dim=2, deg=2). v13: k_ag2 paired-node edge tiles (lanes
// 0-31 = node A, 32-63 = node B) -> per-edge VALU ~halved for deg<=32 nodes.
// 8B edge records; fused MFMA agg+GEMM; MFMA final MLP.
// ---------------------------------------------------------------------------

typedef _Float16 half8 __attribute__((ext_vector_type(8)));
typedef _Float16 half4 __attribute__((ext_vector_type(4)));
typedef float    f32x4 __attribute__((ext_vector_type(4)));
typedef unsigned uintx2 __attribute__((ext_vector_type(2)));
typedef unsigned uintx4 __attribute__((ext_vector_type(4)));

#define ACHUNK 4096   // edges per partition WG (16 per thread)

__device__ __forceinline__ void bspline4(float a, float B[4]) {
    a = fminf(fmaxf(a, 0.f), 1.f);
    float v  = a * 2.0f;          // K - DEG = 2
    float kv = floorf(v);
    float t  = v - kv;
    int   ik = (int)kv;           // 0..2
    float b0 = 0.5f * (1.f - t) * (1.f - t);
    float b1 = (t - t * t) + 0.5f;
    float b2 = 0.5f * t * t;
    int c0 = ik;
    int c1 = ik + 1;
    int c2 = ik + 2; if (c2 > 3) c2 = 3;
#pragma unroll
    for (int j = 0; j < 4; ++j)
        B[j] = (c0 == j ? b0 : 0.f) + (c1 == j ? b1 : 0.f) + (c2 == j ? b2 : 0.f);
}

__device__ __forceinline__ float eluf(float x) {
    return x > 0.f ? x : expm1f(x);
}

// ---------------- Phase A: bucketed partition (bucket = dst >> 8) ----------------

__global__ void kA1_hist(const int* __restrict__ dst, int E, int* __restrict__ cnt,
                         int nWG, int NBUK) {
    extern __shared__ int hist[];   // NBUK ints
    int wg = blockIdx.x, tid = threadIdx.x;
    for (int b = tid; b < NBUK; b += 256) hist[b] = 0;
    __syncthreads();
    int base = wg * ACHUNK;
    int end  = base + ACHUNK; if (end > E) end = E;
    for (int i = base + tid; i < end; i += 256)
        atomicAdd(&hist[dst[i] >> 8], 1);
    __syncthreads();
    for (int b = tid; b < NBUK; b += 256) cnt[b * nWG + wg] = hist[b];
}

__global__ void k_scan1(const int* __restrict__ in, int M,
                        int* __restrict__ outp, int* __restrict__ blockSums) {
    __shared__ int wsum[4];
    int tid  = threadIdx.x;
    int base = blockIdx.x * 1024 + tid * 4;
    int d0 = (base + 0) < M ? in[base + 0] : 0;
    int d1 = (base + 1) < M ? in[base + 1] : 0;
    int d2 = (base + 2) < M ? in[base + 2] : 0;
    int d3 = (base + 3) < M ? in[base + 3] : 0;
    int s4 = d0 + d1 + d2 + d3;
    int lane = tid & 63, wid = tid >> 6;
    int inc = s4;
#pragma unroll
    for (int off = 1; off < 64; off <<= 1) {
        int t = __shfl_up(inc, off);
        if (lane >= off) inc += t;
    }
    if (lane == 63) wsum[wid] = inc;
    __syncthreads();
    if (tid == 0) {
        int acc = 0;
#pragma unroll
        for (int w = 0; w < 4; ++w) { int t = wsum[w]; wsum[w] = acc; acc += t; }
    }
    __syncthreads();
    int ebase = wsum[wid] + inc - s4;
    if ((base + 0) < M) outp[base + 0] = ebase;
    if ((base + 1) < M) outp[base + 1] = ebase + d0;
    if ((base + 2) < M) outp[base + 2] = ebase + d0 + d1;
    if ((base + 3) < M) outp[base + 3] = ebase + d0 + d1 + d2;
    if (tid == 255) blockSums[blockIdx.x] = ebase + s4;
}

// capacity 512 (2 elems per thread)
__global__ void k_scan2(const int* __restrict__ blockSums, int NB, int* __restrict__ blockOff) {
    __shared__ int sh[256];
    int tid = threadIdx.x;
    int i0 = 2 * tid, i1 = 2 * tid + 1;
    int a = (i0 < NB) ? blockSums[i0] : 0;
    int b = (i1 < NB) ? blockSums[i1] : 0;
    int p = a + b;
    sh[tid] = p;
    __syncthreads();
    for (int off = 1; off < 256; off <<= 1) {
        int v = (tid >= off) ? sh[tid - off] : 0;
        __syncthreads();
        sh[tid] += v;
        __syncthreads();
    }
    int excl = sh[tid] - p;
    if (i0 < NB) blockOff[i0] = excl;
    if (i1 < NB) blockOff[i1] = excl + a;
}

__global__ void k_scan3b(int* __restrict__ arr, const int* __restrict__ blockOff, int M) {
    int i = blockIdx.x * blockDim.x + threadIdx.x;
    if (i < M) arr[i] += blockOff[i >> 10];
}

// fill pass: whole chunk staged in LDS; reads coalesced-once, writes runs of 8B recs.
__global__ __launch_bounds__(256) void kA2_fill(
    const int* __restrict__ ei, const float* __restrict__ attr, int E,
    const int* __restrict__ offs, int nWG, int NBUK,
    uint2* __restrict__ buf1) {
    extern __shared__ int lds[];
    int*      hist  = lds;                         // NBUK (becomes pref)
    unsigned* recB  = (unsigned*)(hist + NBUK);    // ACHUNK: src|dlow<<18
    unsigned* attrS = recB + ACHUNK;               // ACHUNK: fp16 u|v
    unsigned* meta  = attrS + ACHUNK;              // ACHUNK: i | b<<12
    __shared__ int wsum[4];
    int wg = blockIdx.x, tid = threadIdx.x;
    int base  = wg * ACHUNK;
    int csize = E - base; if (csize > ACHUNK) csize = ACHUNK;

    for (int b = tid; b < NBUK; b += 256) hist[b] = 0;
    __syncthreads();

    int dArr[16], ranks[16];
#pragma unroll
    for (int k = 0; k < 16; ++k) {
        int i = tid + (k << 8);
        if (i < csize) {
            int d = ei[E + base + i];
            dArr[k]  = d;
            ranks[k] = atomicAdd(&hist[d >> 8], 1);
        }
    }
    __syncthreads();

    int IT = (NBUK + 255) >> 8;
    int b0 = tid * IT;
    int lsum = 0;
    for (int k = 0; k < IT; ++k) {
        int b = b0 + k;
        if (b < NBUK) lsum += hist[b];
    }
    int lane = tid & 63, wid = tid >> 6;
    int inc = lsum;
#pragma unroll
    for (int off = 1; off < 64; off <<= 1) {
        int t = __shfl_up(inc, off);
        if (lane >= off) inc += t;
    }
    if (lane == 63) wsum[wid] = inc;
    __syncthreads();
    if (tid == 0) {
        int acc = 0;
#pragma unroll
        for (int w = 0; w < 4; ++w) { int t = wsum[w]; wsum[w] = acc; acc += t; }
    }
    __syncthreads();
    int run = wsum[wid] + inc - lsum;
    for (int k = 0; k < IT; ++k) {
        int b = b0 + k;
        if (b < NBUK) { int h = hist[b]; hist[b] = run; run += h; }
    }
    __syncthreads();   // hist[] now = pref[]

#pragma unroll
    for (int k = 0; k < 16; ++k) {
        int i = tid + (k << 8);
        if (i < csize) {
            int gi = base + i;
            int d  = dArr[k];
            int b  = d >> 8;
            int s  = hist[b] + ranks[k];
            meta[s] = (unsigned)i | ((unsigned)b << 12);
            recB[i] = (unsigned)ei[gi] | ((unsigned)(d & 255) << 18);
            __half2 uv = __floats2half2_rn(attr[2 * gi], attr[2 * gi + 1]);
            attrS[i] = *(const unsigned*)&uv;
        }
    }
    __syncthreads();

    for (int s = tid; s < csize; s += 256) {
        unsigned mt = meta[s];
        int i = mt & 4095;
        int b = mt >> 12;
        uint2 rec;
        rec.x = attrS[i];
        rec.y = recB[i];
        int gpos = offs[b * nWG + wg] + (s - hist[b]);
        buf1[gpos] = rec;
    }
}

// ---------------- Phase B: per-bucket exact-dst sort + rowptr ----------------

__global__ __launch_bounds__(256) void kB_sort(
    const uint2* __restrict__ buf1,
    const int* __restrict__ off, int nWG, int NBUK, int N, int E,
    uint2* __restrict__ edges, int* __restrict__ rowptr) {
    __shared__ int hist[256], pref[256], curs[256];
    __shared__ int sbase, ssize;
    int b = blockIdx.x, tid = threadIdx.x;
    if (tid == 0) {
        int s  = off[b * nWG];
        int e2 = (b + 1 < NBUK) ? off[(b + 1) * nWG] : E;
        sbase = s; ssize = e2 - s;
    }
    hist[tid] = 0;
    __syncthreads();
    int base = sbase, size = ssize;
    for (int i = tid; i < size; i += 256)
        atomicAdd(&hist[(buf1[base + i].y >> 18) & 255], 1);
    __syncthreads();
    if (tid == 0) {
        int acc = 0;
        for (int j = 0; j < 256; ++j) { pref[j] = acc; acc += hist[j]; }
    }
    __syncthreads();
    curs[tid] = pref[tid];
    int node = b * 256 + tid;
    if (node < N) rowptr[node] = base + pref[tid];
    if (b == NBUK - 1 && tid == 0) rowptr[N] = E;
    __syncthreads();
    for (int i = tid; i < size; i += 256) {
        uint2 rec = buf1[base + i];
        int p = atomicAdd(&curs[(rec.y >> 18) & 255], 1);
        edges[base + p] = rec;
    }
}

// ---------------- w2 + root2 pre-pack into B-fragment order (fp16) ----------------
// agg p = k*32 + ch  ->  K-step s contributes k=s, ch=(l>>4)*8+j.

__global__ void k_w2pack(const float* __restrict__ w2, const float* __restrict__ root2,
                         _Float16* __restrict__ w2f) {
    int f = blockIdx.x * blockDim.x + threadIdx.x;
    int stride = gridDim.x * blockDim.x;
    for (; f < 34816; f += stride) {
        int j = f & 7, l = (f >> 3) & 63, t = (f >> 9) & 3;
        int o = t * 16 + (l & 15);
        float v;
        if (f < 32768) {
            int s  = f >> 11;                     // K-step == basis k
            int ch = ((l >> 4) << 3) + j;         // 0..31
            v = w2[(s * 32 + ch) * 64 + o];
        } else {
            int ci = ((l >> 4) << 3) + j;
            v = root2[ci * 64 + o];
        }
        w2f[f] = (_Float16)v;
    }
}

// ---------------- fc1w pre-pack into B-fragment order (fp16) ----------------

__global__ void k_fcpack(const float* __restrict__ fc1w, _Float16* __restrict__ fc1wf) {
    int f = blockIdx.x * blockDim.x + threadIdx.x;
    if (f >= 8192) return;
    int j = f & 7, l = (f >> 3) & 63, t = (f >> 9) & 7, s = f >> 12;
    int k = s * 32 + ((l >> 4) << 3) + j;
    int o = t * 16 + (l & 15);
    fc1wf[f] = (_Float16)fc1w[k * 128 + o];
}

// ---------------- Layer 1 conv (in=1 -> out=32), thread per node, fp16 out ----------------

__global__ void k_conv1(const float* __restrict__ x, const int* __restrict__ rowptr,
                        const uint2* __restrict__ edges,
                        const float* __restrict__ w1, const float* __restrict__ root1,
                        const float* __restrict__ b1, _Float16* __restrict__ h1h, int N) {
    __shared__ float w1s[16 * 32];
    __shared__ float r1s[32], b1s[32];
    int tid = threadIdx.x;
    for (int i = tid; i < 512; i += blockDim.x) w1s[i] = w1[i];
    if (tid < 32) { r1s[tid] = root1[tid]; b1s[tid] = b1[tid]; }
    __syncthreads();
    int n = blockIdx.x * blockDim.x + tid;
    if (n >= N) return;
    float agg[16] = {};
    int s = rowptr[n], e = rowptr[n + 1];

#define P1(rec, xs) { \
    float2 uv = __half22float2(*(const __half2*)&rec.x); \
    float bu[4], bv[4]; \
    bspline4(uv.x, bu); bspline4(uv.y, bv); \
    float t0 = (xs) * bv[0], t1 = (xs) * bv[1], t2 = (xs) * bv[2], t3 = (xs) * bv[3]; \
    agg[0]  += bu[0] * t0; agg[1]  += bu[1] * t0; agg[2]  += bu[2] * t0; agg[3]  += bu[3] * t0; \
    agg[4]  += bu[0] * t1; agg[5]  += bu[1] * t1; agg[6]  += bu[2] * t1; agg[7]  += bu[3] * t1; \
    agg[8]  += bu[0] * t2; agg[9]  += bu[1] * t2; agg[10] += bu[2] * t2; agg[11] += bu[3] * t2; \
    agg[12] += bu[0] * t3; agg[13] += bu[1] * t3; agg[14] += bu[2] * t3; agg[15] += bu[3] * t3; }

    int j = s;
    for (; j + 3 < e; j += 4) {
        uint2 r0 = edges[j], r1 = edges[j + 1], r2 = edges[j + 2], r3 = edges[j + 3];
        float x0 = x[r0.y & 0x3FFFF], x1 = x[r1.y & 0x3FFFF];
        float x2 = x[r2.y & 0x3FFFF], x3 = x[r3.y & 0x3FFFF];
        P1(r0, x0); P1(r1, x1); P1(r2, x2); P1(r3, x3);
    }
    for (; j < e; ++j) {
        uint2 r = edges[j];
        float xs = x[r.y & 0x3FFFF];
        P1(r, xs);
    }
#undef P1

    float xn = x[n];
    _Float16* hp = h1h + (size_t)n * 32;
#pragma unroll
    for (int o8 = 0; o8 < 4; ++o8) {
        half8 hv;
#pragma unroll
        for (int oo = 0; oo < 8; ++oo) {
            int o = o8 * 8 + oo;
            float acc = b1s[o] + xn * r1s[o];
#pragma unroll
            for (int k = 0; k < 16; ++k) acc += agg[k] * w1s[k * 32 + o];
            hv[oo] = (_Float16)acc;
        }
        *(half8*)(hp + o8 * 8) = hv;
    }
}

// ---------------- BatchNorm (fp16 input stats) ----------------

template <int C>
__global__ void k_bnstath(const _Float16* __restrict__ h, int N, double* __restrict__ sums) {
    __shared__ float sh1[C], sh2[C];
    int tid  = blockIdx.x * blockDim.x + threadIdx.x;
    int c    = tid & (C - 1);
    int row  = tid / C;
    int rstr = (gridDim.x * blockDim.x) / C;
    float s1 = 0.f, s2 = 0.f;
    for (int r = row; r < N; r += rstr) {
        float v = (float)h[(size_t)r * C + c];
        s1 += v; s2 += v * v;
    }
    if (threadIdx.x < C) { sh1[threadIdx.x] = 0.f; sh2[threadIdx.x] = 0.f; }
    __syncthreads();
    atomicAdd(&sh1[c], s1);
    atomicAdd(&sh2[c], s2);
    __syncthreads();
    if (threadIdx.x < C) {
        atomicAdd(&sums[threadIdx.x],     (double)sh1[threadIdx.x]);
        atomicAdd(&sums[C + threadIdx.x], (double)sh2[threadIdx.x]);
    }
}

__global__ void k_bnfinal(const double* __restrict__ sums, const float* __restrict__ gamma,
                          const float* __restrict__ beta, int C, int N, float* __restrict__ scsh) {
    int c = threadIdx.x;
    if (c < C) {
        double m   = sums[c] / (double)N;
        double var = sums[C + c] / (double)N - m * m;
        float vpe  = (float)var + 1e-5f;
        float sc   = gamma[c] / sqrtf(vpe);
        scsh[c]     = sc;
        scsh[C + c] = beta[c] - (float)m * sc;
    }
}

// BN + ELU for h1h (C=32), in place fp16
__global__ void k_bnelu32h(_Float16* __restrict__ hh, int N, const float* __restrict__ scsh) {
    int total = N * 4;
    int i = blockIdx.x * blockDim.x + threadIdx.x;
    int stride = gridDim.x * blockDim.x;
    for (; i < total; i += stride) {
        half8 v = *(half8*)(hh + (size_t)i * 8);
        int c0 = (i * 8) & 31;
        half8 r;
#pragma unroll
        for (int j = 0; j < 8; ++j)
            r[j] = (_Float16)eluf((float)v[j] * scsh[c0 + j] + scsh[32 + c0 + j]);
        *(half8*)(hh + (size_t)i * 8) = r;
    }
}

// ---------------- Layer 2 fused: MFMA aggregation + GEMM (k_ag2) ----------------
// Paired-node tiles: lanes 0-31 = node A's 32-edge window, lanes 32-63 = node B's.
// Per iteration: 4 MFMAs (A-pair even/odd ch, B-pair). C0 even channels, C1 odd.

__global__ __launch_bounds__(256) void k_ag2(
    const _Float16* __restrict__ h1h, const int* __restrict__ rowptr,
    const uint2* __restrict__ edges, const _Float16* __restrict__ w2f,
    const float* __restrict__ b2, _Float16* __restrict__ out2h, int N) {
    __shared__ __align__(16) unsigned aggW[16][262];
    __shared__ __align__(16) _Float16 basisL[4][16][76];
    __shared__ __align__(16) int      srcL[4][64];
    int tid = threadIdx.x, l = tid & 63, w = tid >> 6;
    int g = l >> 4, m = l & 15;
    int n0 = blockIdx.x * 16;
    const unsigned* h32 = (const unsigned*)h1h;
    int kh_l = l >> 5, ll = l & 31;

    // ---- phase 1: aggregation, 2 nodes per wave-iteration ----
    for (int q = 0; q < 2; ++q) {
        int rowA = w * 4 + q * 2;
        int rowB = rowA + 1;
        int nA = n0 + rowA, nB = n0 + rowB;
        int sA = 0, eA = 0, sB = 0, eB = 0;
        if (nA < N) {
            sA = __builtin_amdgcn_readfirstlane(rowptr[nA]);
            eA = __builtin_amdgcn_readfirstlane(rowptr[nA + 1]);
        }
        if (nB < N) {
            sB = __builtin_amdgcn_readfirstlane(rowptr[nB]);
            eB = __builtin_amdgcn_readfirstlane(rowptr[nB + 1]);
        }
        int degA = eA - sA, degB = eB - sB;
        int dmax = degA > degB ? degA : degB;
        int iters = (dmax + 31) >> 5;
        f32x4 CA0 = {0.f, 0.f, 0.f, 0.f}, CA1 = CA0, CB0 = CA0, CB1 = CA0;
        int sX   = kh_l ? sB : sA;
        int degX = kh_l ? degB : degA;
        for (int it = 0; it < iters; ++it) {
            int off32 = it * 32;
            int pos = off32 + ll;
            bool act = pos < degX;
            int idx = sX + (act ? pos : (degX > 0 ? degX - 1 : 0));
            uint2 rec = edges[idx];
            srcL[w][l] = (int)(rec.y & 0x3FFFFu);
            float2 uvf = __half22float2(*(const __half2*)&rec.x);
            float bu[4], bv[4];
            bspline4(uvf.x, bu);
            bspline4(uvf.y, bv);
#pragma unroll
            for (int kv = 0; kv < 4; ++kv)
#pragma unroll
                for (int ku = 0; ku < 4; ++ku)
                    basisL[w][kv * 4 + ku][l] = (_Float16)(bu[ku] * bv[kv]);
#pragma unroll
            for (int kh = 0; kh < 2; ++kh) {
                int ebase = kh * 32 + g * 8;
                half4 alo = *(const half4*)&basisL[w][m][ebase];
                half4 ahi = *(const half4*)&basisL[w][m][ebase + 4];
                half8 a;
#pragma unroll
                for (int i = 0; i < 4; ++i) { a[i] = alo[i]; a[4 + i] = ahi[i]; }
                int dX = kh ? degB : degA;
                unsigned u[8];
#pragma unroll
                for (int j = 0; j < 8; ++j) {
                    int sj = srcL[w][ebase + j];
                    bool aj = (off32 + g * 8 + j) < dX;
                    unsigned uv = h32[(size_t)sj * 16 + m];
                    u[j] = aj ? uv : 0u;
                }
                uintx4 p0, p1;
#pragma unroll
                for (int tt = 0; tt < 4; ++tt) {
                    p0[tt] = (u[2 * tt] & 0xFFFFu) | (u[2 * tt + 1] << 16);
                    p1[tt] = (u[2 * tt] >> 16) | (u[2 * tt + 1] & 0xFFFF0000u);
                }
                half8 b0 = __builtin_bit_cast(half8, p0);
                half8 b1 = __builtin_bit_cast(half8, p1);
                if (kh == 0) {
                    CA0 = __builtin_amdgcn_mfma_f32_16x16x32_f16(a, b0, CA0, 0, 0, 0);
                    CA1 = __builtin_amdgcn_mfma_f32_16x16x32_f16(a, b1, CA1, 0, 0, 0);
                } else {
                    CB0 = __builtin_amdgcn_mfma_f32_16x16x32_f16(a, b0, CB0, 0, 0, 0);
                    CB1 = __builtin_amdgcn_mfma_f32_16x16x32_f16(a, b1, CB1, 0, 0, 0);
                }
            }
        }
        if (nA < N) {
#pragma unroll
            for (int r = 0; r < 4; ++r) {
                __half2 hp = __floats2half2_rn(CA0[r], CA1[r]);
                aggW[rowA][(g * 4 + r) * 16 + m] = *(const unsigned*)&hp;
            }
        }
        if (nB < N) {
#pragma unroll
            for (int r = 0; r < 4; ++r) {
                __half2 hp = __floats2half2_rn(CB0[r], CB1[r]);
                aggW[rowB][(g * 4 + r) * 16 + m] = *(const unsigned*)&hp;
            }
        }
    }
    __syncthreads();

    // ---- phase 2: [16 nodes x 544] @ w2f -> out2h ----
    f32x4 acc = {0.f, 0.f, 0.f, 0.f};
#pragma unroll
    for (int s = 0; s < 16; ++s) {
        uintx2 a01 = *(const uintx2*)&aggW[m][s * 16 + g * 4];
        uintx2 a23 = *(const uintx2*)&aggW[m][s * 16 + g * 4 + 2];
        uintx4 av; av[0] = a01[0]; av[1] = a01[1]; av[2] = a23[0]; av[3] = a23[1];
        half8 a = __builtin_bit_cast(half8, av);
        half8 b = *(const half8*)&w2f[(size_t)(((s * 4 + w) * 64) + l) * 8];
        acc = __builtin_amdgcn_mfma_f32_16x16x32_f16(a, b, acc, 0, 0, 0);
    }
    {
        int nn = n0 + m; if (nn > N - 1) nn = N - 1;
        half8 a = *(const half8*)&h1h[(size_t)nn * 32 + g * 8];
        half8 b = *(const half8*)&w2f[(size_t)(((64 + w) * 64) + l) * 8];
        acc = __builtin_amdgcn_mfma_f32_16x16x32_f16(a, b, acc, 0, 0, 0);
    }
    int o = w * 16 + m;
    float bb = b2[o];
#pragma unroll
    for (int r = 0; r < 4; ++r) {
        int node = n0 + g * 4 + r;
        if (node < N) out2h[(size_t)node * 64 + o] = (_Float16)(acc[r] + bb);
    }
}

// ---------------- Final MLP via MFMA ----------------

__global__ __launch_bounds__(256) void k_fcm(
    const _Float16* __restrict__ out2h, const _Float16* __restrict__ fc1wf,
    const float* __restrict__ scsh, const float* __restrict__ fc1b,
    const float* __restrict__ fc2w, const float* __restrict__ fc2b,
    float* __restrict__ out, int N, int ntiles) {
    __shared__ _Float16 fw[8192];
    __shared__ float scs[64], shs[64], b1s[128], w2sv[128];
    int tid = threadIdx.x;
    {
        const uint4* s4 = (const uint4*)fc1wf;
        uint4* d4 = (uint4*)fw;
        for (int i = tid; i < 1024; i += 256) d4[i] = s4[i];
    }
    if (tid < 128) { b1s[tid] = fc1b[tid]; w2sv[tid] = fc2w[tid]; }
    if (tid < 64)  { scs[tid] = scsh[tid]; shs[tid] = scsh[64 + tid]; }
    __syncthreads();
    const half8* bp = (const half8*)fw;
    int l = tid & 63, w = tid >> 6;
    int g = l >> 4, m = l & 15, klo = g * 8;
    float f2b = fc2b[0];
    for (int tile = blockIdx.x * 4 + w; tile < ntiles; tile += gridDim.x * 4) {
        int base = tile * 16;
        int arow = base + m; if (arow > N - 1) arow = N - 1;
        const half8* hp = (const half8*)(out2h + (size_t)arow * 64 + klo);
        half8 r0 = hp[0];
        half8 r1 = hp[4];
        half8 a0, a1;
#pragma unroll
        for (int j = 0; j < 8; ++j) {
            int c0 = klo + j, c1 = 32 + klo + j;
            a0[j] = (_Float16)eluf((float)r0[j] * scs[c0] + shs[c0]);
            a1[j] = (_Float16)eluf((float)r1[j] * scs[c1] + shs[c1]);
        }
        f32x4 acc[8];
#pragma unroll
        for (int t = 0; t < 8; ++t) {
            f32x4 z = {0.f, 0.f, 0.f, 0.f};
            acc[t] = __builtin_amdgcn_mfma_f32_16x16x32_f16(a0, bp[t * 64 + l], z, 0, 0, 0);
            acc[t] = __builtin_amdgcn_mfma_f32_16x16x32_f16(a1, bp[(8 + t) * 64 + l], acc[t], 0, 0, 0);
        }
#pragma unroll
        for (int r = 0; r < 4; ++r) {
            float sum = 0.f;
#pragma unroll
            for (int t = 0; t < 8; ++t) {
                int o = t * 16 + m;
                sum += eluf(acc[t][r] + b1s[o]) * w2sv[o];
            }
            sum += __shfl_xor(sum, 1);
            sum += __shfl_xor(sum, 2);
            sum += __shfl_xor(sum, 4);
            sum += __shfl_xor(sum, 8);
            int node = base + g * 4 + r;
            if (m == 0 && node < N) out[node] = sum + f2b;
        }
    }
}

// ---------------------------------------------------------------------------

extern "C" void kernel_launch(void* const* d_in, const int* in_sizes, int n_in,
                              void* d_out, int out_size, void* d_ws, size_t ws_size,
                              hipStream_t stream) {
    const float* x     = (const float*)d_in[0];
    const int*   ei    = (const int*)  d_in[1];
    const float* attr  = (const float*)d_in[2];
    const float* w1    = (const float*)d_in[3];
    const float* root1 = (const float*)d_in[4];
    const float* b1    = (const float*)d_in[5];
    const float* g1    = (const float*)d_in[6];
    const float* be1   = (const float*)d_in[7];
    const float* w2    = (const float*)d_in[8];
    const float* root2 = (const float*)d_in[9];
    const float* b2    = (const float*)d_in[10];
    const float* g2    = (const float*)d_in[11];
    const float* be2   = (const float*)d_in[12];
    const float* fc1w  = (const float*)d_in[13];
    const float* fc1b  = (const float*)d_in[14];
    const float* fc2w  = (const float*)d_in[15];
    const float* fc2b  = (const float*)d_in[16];
    float* out = (float*)d_out;

    int N = in_sizes[0];          // 150000
    int E = in_sizes[1] / 2;      // 3000000

    int nWG  = (E + ACHUNK - 1) / ACHUNK;   // 733
    int NBUK = (N + 255) >> 8;              // 586
    int M    = NBUK * nWG;                  // ~430k

    char* ws = (char*)d_ws;
    size_t off = 0;
    auto alloc = [&](size_t bytes) -> void* {
        void* p = ws + off;
        off = (off + bytes + 255) & ~(size_t)255;
        return p;
    };
    int*      rowptr    = (int*)     alloc((size_t)(N + 1) * 4);
    int*      blockSums = (int*)     alloc(1024 * 4);
    int*      blockOff  = (int*)     alloc(1024 * 4);
    double*   bnsum1    = (double*)  alloc(128 * 8);
    double*   bnsum2    = (double*)  alloc(128 * 8);
    float*    scsh1     = (float*)   alloc(64 * 4);
    float*    scsh2     = (float*)   alloc(128 * 4);
    _Float16* w2f       = (_Float16*)alloc(34816 * 2);
    _Float16* fc1wf     = (_Float16*)alloc(8192 * 2);
    int*      cnt       = (int*)     alloc((size_t)M * 4);
    int*      offs      = (int*)     alloc((size_t)M * 4);
    uint2*    edges     = (uint2*)   alloc((size_t)E * 8);        // 24 MB
    size_t    Roff      = off;              // start of aliasable region
    _Float16* h1h       = (_Float16*)alloc((size_t)N * 32 * 2);   //  9.6 MB
    _Float16* out2h     = (_Float16*)alloc((size_t)N * 64 * 2);   // 19.2 MB
    // buf1 aliases [h1h|out2h] (24 MB <= 28.8 MB); dead before conv1 runs
    uint2* buf1 = (uint2*)(ws + Roff);
    (void)n_in; (void)out_size; (void)ws_size;

    hipMemsetAsync(bnsum1, 0, 128 * 8, stream);
    hipMemsetAsync(bnsum2, 0, 128 * 8, stream);

    size_t ldsA1 = (size_t)NBUK * 4;
    size_t ldsA2 = (size_t)NBUK * 4 + (size_t)ACHUNK * 12;
    int NBs = (M + 1023) / 1024;            // ~420 <= 512

    k_w2pack<<<136, 256, 0, stream>>>(w2, root2, w2f);
    k_fcpack<<<32, 256, 0, stream>>>(fc1w, fc1wf);
    kA1_hist<<<nWG, 256, ldsA1, stream>>>(ei + E, E, cnt, nWG, NBUK);
    k_scan1<<<NBs, 256, 0, stream>>>(cnt, M, offs, blockSums);
    k_scan2<<<1, 256, 0, stream>>>(blockSums, NBs, blockOff);
    k_scan3b<<<(M + 255) / 256, 256, 0, stream>>>(offs, blockOff, M);
    kA2_fill<<<nWG, 256, ldsA2, stream>>>(ei, attr, E, offs, nWG, NBUK, buf1);
    kB_sort<<<NBUK, 256, 0, stream>>>(buf1, offs, nWG, NBUK, N, E, edges, rowptr);

    k_conv1<<<(N + 255) / 256, 256, 0, stream>>>(x, rowptr, edges, w1, root1, b1, h1h, N);
    k_bnstath<32><<<256, 256, 0, stream>>>(h1h, N, bnsum1);
    k_bnfinal<<<1, 64, 0, stream>>>(bnsum1, g1, be1, 32, N, scsh1);
    k_bnelu32h<<<1024, 256, 0, stream>>>(h1h, N, scsh1);

    k_ag2<<<(N + 15) / 16, 256, 0, stream>>>(h1h, rowptr, edges, w2f, b2, out2h, N);

    k_bnstath<64><<<256, 256, 0, stream>>>(out2h, N, bnsum2);
    k_bnfinal<<<1, 64, 0, stream>>>(bnsum2, g2, be2, 64, N, scsh2);

    int ntilesF = (N + 15) / 16;
    int gridF = (ntilesF + 3) / 4; if (gridF > 2344) gridF = 2344;
    k_fcm<<<gridF, 256, 0, stream>>>(out2h, fc1wf, scsh2, fc1b, fc2w, fc2b, out, N, ntilesF);
}